// Round 1
// baseline (155.493 us; speedup 1.0000x reference)
//
#include <hip/hip_runtime.h>

// LIF neuron scan: v = v*0.5 + x[t]; s = (v - 0.5 > 0); v -= s*0.5
// One thread per (batch, neuron) row; T=100 contiguous floats per row.
// Memory-bound: 420 MB total traffic -> ~67 us roofline @ 6.3 TB/s.

#define T_STEPS   100
#define T_VEC     25      // 100 / 4
#define DECAY     0.5f
#define VTH       0.5f

__global__ __launch_bounds__(256) void lif_kernel(const float* __restrict__ x,
                                                  float* __restrict__ out,
                                                  int n_rows) {
    int row = blockIdx.x * blockDim.x + threadIdx.x;
    if (row >= n_rows) return;

    const float4* __restrict__ xr   = reinterpret_cast<const float4*>(x)   + (size_t)row * T_VEC;
    float4* __restrict__       orow = reinterpret_cast<float4*>(out)       + (size_t)row * T_VEC;

    float v = 0.0f;

    #pragma unroll
    for (int j = 0; j < T_VEC; ++j) {
        float4 xv = xr[j];
        float xs[4] = {xv.x, xv.y, xv.z, xv.w};
        float ss[4];

        #pragma unroll
        for (int k = 0; k < 4; ++k) {
            // v*0.5 is exact (mul by power of 2), so FMA == mul-then-add bitwise.
            v = v * DECAY + xs[k];
            float d = v - VTH;
            float sk = (d > 0.0f) ? 1.0f : 0.0f;
            v -= sk * VTH;   // sk*VTH in {0, 0.5} exact
            ss[k] = sk;
        }

        float4 sv;
        sv.x = ss[0]; sv.y = ss[1]; sv.z = ss[2]; sv.w = ss[3];
        orow[j] = sv;
    }
}

extern "C" void kernel_launch(void* const* d_in, const int* in_sizes, int n_in,
                              void* d_out, int out_size, void* d_ws, size_t ws_size,
                              hipStream_t stream) {
    const float* x = (const float*)d_in[0];
    float* out = (float*)d_out;

    int n_rows = in_sizes[0] / T_STEPS;   // 32 * 16384 = 524288
    int block = 256;
    int grid = (n_rows + block - 1) / block;  // 2048

    lif_kernel<<<grid, block, 0, stream>>>(x, out, n_rows);
}